// Round 2
// baseline (505.528 us; speedup 1.0000x reference)
//
#include <hip/hip_runtime.h>

typedef __attribute__((ext_vector_type(8))) short short8;
typedef __attribute__((ext_vector_type(4))) float f32x4;

#define GLOAD16(g, l) __builtin_amdgcn_global_load_lds(                         \
    (const __attribute__((address_space(1))) void*)(g),                          \
    (__attribute__((address_space(3))) void*)(l), 16, 0, 0)

__device__ __forceinline__ float bf2f(unsigned short u) {
  union { unsigned int i; float f; } c; c.i = ((unsigned int)u) << 16; return c.f;
}
__device__ __forceinline__ unsigned short f2bf(float f) {
  union { float f; unsigned int i; } c; c.f = f;
  unsigned int u = c.i;
  u = (u + 0x7fffu + ((u >> 16) & 1u)) >> 16;
  return (unsigned short)u;
}

// ---------------------------------------------------------------- fp32 -> bf16
__global__ __launch_bounds__(256) void cvt_f32_bf16(const float* __restrict__ src,
                                                    unsigned short* __restrict__ dst,
                                                    int n8) {
  int i = blockIdx.x * 256 + threadIdx.x;
  if (i >= n8) return;
  const float4* s4 = (const float4*)src + (long)i * 2;
  float4 a = s4[0], b = s4[1];
  short8 o;
  o[0] = (short)f2bf(a.x); o[1] = (short)f2bf(a.y);
  o[2] = (short)f2bf(a.z); o[3] = (short)f2bf(a.w);
  o[4] = (short)f2bf(b.x); o[5] = (short)f2bf(b.y);
  o[6] = (short)f2bf(b.z); o[7] = (short)f2bf(b.w);
  *((short8*)dst + i) = o;
}

// ------------------------------------------------- C = A(MxK) * B(NxK)^T  (bf16)
// m97 structure: 128x128 tile, BK=64, 4 waves (2x2), global_load_lds w=16,
// XOR-swizzle ((row&7)<<4) on byte offsets; linear LDS dest + pre-swizzled
// global source + swizzled ds_read (rule #21).
template<int OUT_F32>
__global__ __launch_bounds__(256) void gemm_bt(const unsigned short* __restrict__ A,
                                               const unsigned short* __restrict__ B,
                                               void* __restrict__ Cout,
                                               int M, int N, int K) {
  __shared__ __attribute__((aligned(16))) unsigned short Ah[128 * 64];
  __shared__ __attribute__((aligned(16))) unsigned short Bh[128 * 64];
  const int tid = threadIdx.x;
  const int l = tid & 63;
  const int w = tid >> 6;
  const int wm = w >> 1, wn = w & 1;
  const long brow = (long)blockIdx.y * 128;
  const long bcol = (long)blockIdx.x * 128;

  f32x4 acc[4][4];
#pragma unroll
  for (int i = 0; i < 4; ++i)
#pragma unroll
    for (int j = 0; j < 4; ++j) acc[i][j] = (f32x4){0.f, 0.f, 0.f, 0.f};

  const int srow = tid >> 3;   // + i*32 : tile row (128B rows)
  const int sg = tid & 7;      // 16B granule within row
  const int lwb = w << 10;     // wave-uniform LDS byte base

  for (int k0 = 0; k0 < K; k0 += 64) {
    __syncthreads();
#pragma unroll
    for (int i = 0; i < 4; ++i) {
      const int r = srow + i * 32;
      const int gp = (sg ^ (r & 7)) * 8;   // inverse-swizzled source granule
      GLOAD16(A + (brow + r) * K + k0 + gp, (char*)Ah + lwb + i * 4096);
      GLOAD16(B + (bcol + r) * K + k0 + gp, (char*)Bh + lwb + i * 4096);
    }
    __syncthreads();
#pragma unroll
    for (int ks = 0; ks < 2; ++ks) {
      short8 af[4], bf[4];
#pragma unroll
      for (int mi = 0; mi < 4; ++mi) {
        const int row = wm * 64 + mi * 16 + (l & 15);
        const int byt = (row * 128 + (l >> 4) * 16 + ks * 64) ^ ((row & 7) << 4);
        af[mi] = *(const short8*)((const char*)Ah + byt);
      }
#pragma unroll
      for (int nj = 0; nj < 4; ++nj) {
        const int row = wn * 64 + nj * 16 + (l & 15);
        const int byt = (row * 128 + (l >> 4) * 16 + ks * 64) ^ ((row & 7) << 4);
        bf[nj] = *(const short8*)((const char*)Bh + byt);
      }
#pragma unroll
      for (int mi = 0; mi < 4; ++mi)
#pragma unroll
        for (int nj = 0; nj < 4; ++nj)
          acc[mi][nj] = __builtin_amdgcn_mfma_f32_16x16x32_bf16(af[mi], bf[nj],
                                                                acc[mi][nj], 0, 0, 0);
    }
  }

  const long rb = brow + wm * 64 + (l >> 4) * 4;
  const long cb = bcol + wn * 64 + (l & 15);
#pragma unroll
  for (int mi = 0; mi < 4; ++mi)
#pragma unroll
    for (int nj = 0; nj < 4; ++nj)
#pragma unroll
      for (int j = 0; j < 4; ++j) {
        const long row = rb + mi * 16 + j;
        const long col = cb + nj * 16;
        if (OUT_F32) ((float*)Cout)[row * N + col] = acc[mi][nj][j];
        else ((unsigned short*)Cout)[row * N + col] = f2bf(acc[mi][nj][j]);
      }
}

// ------------------------------------------------------------- RoPE on q,k
// qkv layout: (B*T, 3*2048); q at col [0,2048), k at [2048,4096).
__global__ __launch_bounds__(256) void rope_qk(unsigned short* __restrict__ qkv) {
  int gid = blockIdx.x * 256 + threadIdx.x;  // B*T*H*64 = 4194304 threads
  int m = gid >> 10;
  int h = (gid >> 6) & 15;
  int d = gid & 63;
  int t = m & 2047;
  long base = (long)m * 6144 + h * 128;
  // div = 10000^(-d/64) = exp(-(2d) * ln(10000)/128)
  float inv = expf(-(float)(2 * d) * 0.07195578415606394f);
  float ang = (float)t * inv;
  float s = sinf(ang), c = cosf(ang);
  float q1 = bf2f(qkv[base + d]),        q2 = bf2f(qkv[base + 64 + d]);
  qkv[base + d]        = f2bf(q1 * c - q2 * s);
  qkv[base + 64 + d]   = f2bf(q2 * c + q1 * s);
  float k1 = bf2f(qkv[base + 2048 + d]), k2 = bf2f(qkv[base + 2048 + 64 + d]);
  qkv[base + 2048 + d]      = f2bf(k1 * c - k2 * s);
  qkv[base + 2048 + 64 + d] = f2bf(k2 * c + k1 * s);
}

// --------------------------------------------- V (b,t,h,d) -> Vt (bh, d, t)
__global__ __launch_bounds__(256) void transpose_v(const unsigned short* __restrict__ qkv,
                                                   unsigned short* __restrict__ vt) {
  __shared__ __attribute__((aligned(16))) unsigned short tile[32][136];
  int tid = threadIdx.x;
  int t0 = blockIdx.x * 32;
  int bh = blockIdx.y;
  int b = bh >> 4, h = bh & 15;
  {
    int tt = tid >> 3;
    int dcb = (tid & 7) * 16;
    const unsigned short* src = qkv + (long)(b * 2048 + t0 + tt) * 6144 + 4096 + h * 128 + dcb;
    *(short8*)&tile[tt][dcb]     = *(const short8*)src;
    *(short8*)&tile[tt][dcb + 8] = *(const short8*)(src + 8);
  }
  __syncthreads();
  {
    int d = tid >> 1;
    int ts = (tid & 1) * 16;
    short8 o0, o1;
#pragma unroll
    for (int i = 0; i < 8; ++i) o0[i] = (short)tile[ts + i][d];
#pragma unroll
    for (int i = 0; i < 8; ++i) o1[i] = (short)tile[ts + 8 + i][d];
    unsigned short* dst = vt + (long)bh * 262144 + (long)d * 2048 + t0 + ts;
    *(short8*)dst       = o0;
    *(short8*)(dst + 8) = o1;
  }
}

// ----------------------------------------------------------- flash attention
// grid (32 qtiles, 32 bh); 4 waves, each owns 16 q-rows; KV-step 64.
#define LOG2E 1.4426950408889634f
__global__ __launch_bounds__(256) void flash_attn(const unsigned short* __restrict__ qkv,
                                                  const unsigned short* __restrict__ vt,
                                                  unsigned short* __restrict__ attn) {
  __shared__ __attribute__((aligned(16))) unsigned short Kh[64 * 128];   // 16KB, 256B rows
  __shared__ __attribute__((aligned(16))) unsigned short Vh[128 * 64];   // 16KB, 128B rows
  __shared__ __attribute__((aligned(16))) unsigned short Ph[4][16 * 64]; // 2KB/wave

  const int tid = threadIdx.x;
  const int l = tid & 63;
  const int w = tid >> 6;
  const int qt = (int)(gridDim.x - 1) - (int)blockIdx.x;  // heavy blocks first
  const int bh = blockIdx.y;
  const int b = bh >> 4, h = bh & 15;
  const int q0 = qt * 64;
  const float scale = 0.08838834764831845f;  // 1/sqrt(128)

  // Q fragments, prescaled by 1/sqrt(D)
  short8 qf[4];
  {
    const int qrow = q0 + w * 16 + (l & 15);
    const unsigned short* qp = qkv + (long)(b * 2048 + qrow) * 6144 + h * 128 + (l >> 4) * 8;
#pragma unroll
    for (int dc = 0; dc < 4; ++dc) {
      short8 v = *(const short8*)(qp + dc * 32);
#pragma unroll
      for (int j = 0; j < 8; ++j) v[j] = (short)f2bf(bf2f((unsigned short)v[j]) * scale);
      qf[dc] = v;
    }
  }

  f32x4 accO[8];
#pragma unroll
  for (int i = 0; i < 8; ++i) accO[i] = (f32x4){0.f, 0.f, 0.f, 0.f};
  float mrow[4], lrow[4];
#pragma unroll
  for (int j = 0; j < 4; ++j) { mrow[j] = -INFINITY; lrow[j] = 0.f; }

  const int kvEnd = q0 + 64;
  for (int kv0 = 0; kv0 < kvEnd; kv0 += 64) {
    __syncthreads();
    // stage K (64 rows x 256B) and Vt (128 rows x 128B), swizzled source
#pragma unroll
    for (int i = 0; i < 4; ++i) {
      const int kr = (tid >> 4) + i * 16;
      const int kgp = ((tid & 15) ^ (kr & 7)) * 8;
      GLOAD16(qkv + (long)(b * 2048 + kv0 + kr) * 6144 + 2048 + h * 128 + kgp,
              (char*)Kh + (w << 10) + i * 4096);
      const int vr = (tid >> 3) + i * 32;
      const int vgp = ((tid & 7) ^ (vr & 7)) * 8;
      GLOAD16(vt + (long)bh * 262144 + (long)vr * 2048 + kv0 + vgp,
              (char*)Vh + (w << 10) + i * 4096);
    }
    __syncthreads();

    // S = (Q*scale) K^T  : 4 col-tiles x 4 d-chunks
    f32x4 s[4];
#pragma unroll
    for (int kvt = 0; kvt < 4; ++kvt) {
      s[kvt] = (f32x4){0.f, 0.f, 0.f, 0.f};
#pragma unroll
      for (int dc = 0; dc < 4; ++dc) {
        const int krow = kvt * 16 + (l & 15);
        const int byt = (krow * 256 + (l >> 4) * 16 + dc * 64) ^ ((krow & 7) << 4);
        short8 kf = *(const short8*)((const char*)Kh + byt);
        s[kvt] = __builtin_amdgcn_mfma_f32_16x16x32_bf16(qf[dc], kf, s[kvt], 0, 0, 0);
      }
    }

    // causal mask + row max
    const int qrc = q0 + w * 16 + ((l >> 4) << 2);
    float mx[4];
#pragma unroll
    for (int j = 0; j < 4; ++j) mx[j] = -1e30f;
#pragma unroll
    for (int kvt = 0; kvt < 4; ++kvt) {
      const int kvcol = kv0 + kvt * 16 + (l & 15);
#pragma unroll
      for (int j = 0; j < 4; ++j) {
        float sv = s[kvt][j];
        if (kvcol > qrc + j) sv = -1e30f;
        s[kvt][j] = sv;
        mx[j] = fmaxf(mx[j], sv);
      }
    }
#pragma unroll
    for (int j = 0; j < 4; ++j) {
      float v = mx[j];
      v = fmaxf(v, __shfl_xor(v, 1));
      v = fmaxf(v, __shfl_xor(v, 2));
      v = fmaxf(v, __shfl_xor(v, 4));
      v = fmaxf(v, __shfl_xor(v, 8));
      mx[j] = v;
    }
    float alpha[4];
#pragma unroll
    for (int j = 0; j < 4; ++j) {
      float mnew = fmaxf(mrow[j], mx[j]);
      alpha[j] = exp2f((mrow[j] - mnew) * LOG2E);
      mrow[j] = mnew;
    }
    // P = exp(S - m), row sums, write P (bf16) to swizzled per-wave LDS tile
    float ps[4] = {0.f, 0.f, 0.f, 0.f};
#pragma unroll
    for (int kvt = 0; kvt < 4; ++kvt) {
#pragma unroll
      for (int j = 0; j < 4; ++j) {
        float p = exp2f((s[kvt][j] - mrow[j]) * LOG2E);
        ps[j] += p;
        const int prow = ((l >> 4) << 2) + j;
        const int pcol = kvt * 16 + (l & 15);
        const int byt = (prow * 128 + pcol * 2) ^ ((prow & 7) << 4);
        *(unsigned short*)((char*)&Ph[w][0] + byt) = f2bf(p);
      }
    }
#pragma unroll
    for (int j = 0; j < 4; ++j) {
      float v = ps[j];
      v += __shfl_xor(v, 1);
      v += __shfl_xor(v, 2);
      v += __shfl_xor(v, 4);
      v += __shfl_xor(v, 8);
      lrow[j] = lrow[j] * alpha[j] + v;
    }
    __syncthreads();  // P visible (also orders next-iter staging)

    // rescale running O, then O += P * Vt
#pragma unroll
    for (int dn = 0; dn < 8; ++dn)
#pragma unroll
      for (int j = 0; j < 4; ++j) accO[dn][j] *= alpha[j];
#pragma unroll
    for (int half = 0; half < 2; ++half) {
      const int prow = (l & 15);
      const int pbyt = (prow * 128 + (l >> 4) * 16 + half * 64) ^ ((prow & 7) << 4);
      short8 pf = *(const short8*)((const char*)&Ph[w][0] + pbyt);
#pragma unroll
      for (int dn = 0; dn < 8; ++dn) {
        const int vrow = dn * 16 + (l & 15);
        const int vbyt = (vrow * 128 + (l >> 4) * 16 + half * 64) ^ ((vrow & 7) << 4);
        short8 vf = *(const short8*)((const char*)Vh + vbyt);
        accO[dn] = __builtin_amdgcn_mfma_f32_16x16x32_bf16(pf, vf, accO[dn], 0, 0, 0);
      }
    }
  }

  // epilogue: O / l  — written in (B,H,T,D) order to match the reference's
  // transpose(0,2,1,3).reshape(B,T,C): flat row b*2048+i of the gemm2 A-matrix
  // is attn[b, h=i>>7, t=(i&127)*16 + (col>>7), d=col&127]  ==  (B,H,T,D) flat.
#pragma unroll
  for (int dn = 0; dn < 8; ++dn)
#pragma unroll
    for (int j = 0; j < 4; ++j) {
      const int qrow = q0 + w * 16 + ((l >> 4) << 2) + j;
      const int d = dn * 16 + (l & 15);
      attn[((long)bh * 2048 + qrow) * 128 + d] = f2bf(accO[dn][j] / lrow[j]);
    }
}

extern "C" void kernel_launch(void* const* d_in, const int* in_sizes, int n_in,
                              void* d_out, int out_size, void* d_ws, size_t ws_size,
                              hipStream_t stream) {
  (void)in_sizes; (void)n_in; (void)out_size; (void)ws_size;
  const float* x  = (const float*)d_in[0];
  const float* qw = (const float*)d_in[1];
  const float* ow = (const float*)d_in[2];
  float* out = (float*)d_out;
  char* ws = (char*)d_ws;

  // workspace overlay (peak 92,274,688 B):
  unsigned short* xb    = (unsigned short*)(ws + 0);          // 16.78 MB (phase 1)
  unsigned short* wqb   = (unsigned short*)(ws + 16777216);   // 25.17 MB (phase 1)
  unsigned short* qkvb  = (unsigned short*)(ws + 41943040);   // 50.33 MB
  unsigned short* vtb   = (unsigned short*)(ws + 0);          // 16.78 MB (phase 2)
  unsigned short* attnb = (unsigned short*)(ws + 16777216);   // 16.78 MB (phase 2, BHTD order)
  unsigned short* wob   = (unsigned short*)(ws + 33554432);   //  8.39 MB (phase 2)

  cvt_f32_bf16<<<4096, 256, 0, stream>>>(x, xb, 1048576);
  cvt_f32_bf16<<<6144, 256, 0, stream>>>(qw, wqb, 1572864);
  gemm_bt<0><<<dim3(48, 32), 256, 0, stream>>>(xb, wqb, (void*)qkvb, 4096, 6144, 2048);
  cvt_f32_bf16<<<2048, 256, 0, stream>>>(ow, wob, 524288);     // after gemm1 (overlays wqb)
  rope_qk<<<16384, 256, 0, stream>>>(qkvb);
  transpose_v<<<dim3(64, 32), 256, 0, stream>>>(qkvb, vtb);
  flash_attn<<<dim3(32, 32), 256, 0, stream>>>(qkvb, vtb, attnb);
  gemm_bt<1><<<dim3(16, 32), 256, 0, stream>>>(attnb, wob, (void*)out, 4096, 2048, 2048);
}

// Round 3
// 428.660 us; speedup vs baseline: 1.1793x; 1.1793x over previous
//
#include <hip/hip_runtime.h>

typedef __attribute__((ext_vector_type(8))) short short8;
typedef __attribute__((ext_vector_type(4))) float f32x4;

#define GLOAD16(g, l) __builtin_amdgcn_global_load_lds(                         \
    (const __attribute__((address_space(1))) void*)(g),                          \
    (__attribute__((address_space(3))) void*)(l), 16, 0, 0)

__device__ __forceinline__ float bf2f(unsigned short u) {
  union { unsigned int i; float f; } c; c.i = ((unsigned int)u) << 16; return c.f;
}
__device__ __forceinline__ unsigned short f2bf(float f) {
  union { float f; unsigned int i; } c; c.f = f;
  unsigned int u = c.i;
  u = (u + 0x7fffu + ((u >> 16) & 1u)) >> 16;
  return (unsigned short)u;
}

// ---------------------------------------------------------------- fp32 -> bf16
__global__ __launch_bounds__(256) void cvt_f32_bf16(const float* __restrict__ src,
                                                    unsigned short* __restrict__ dst,
                                                    int n8) {
  int i = blockIdx.x * 256 + threadIdx.x;
  if (i >= n8) return;
  const float4* s4 = (const float4*)src + (long)i * 2;
  float4 a = s4[0], b = s4[1];
  short8 o;
  o[0] = (short)f2bf(a.x); o[1] = (short)f2bf(a.y);
  o[2] = (short)f2bf(a.z); o[3] = (short)f2bf(a.w);
  o[4] = (short)f2bf(b.x); o[5] = (short)f2bf(b.y);
  o[6] = (short)f2bf(b.z); o[7] = (short)f2bf(b.w);
  *((short8*)dst + i) = o;
}

// ------------------------------------------------- C = A(MxK) * B(NxK)^T  (bf16)
template<int OUT_F32>
__global__ __launch_bounds__(256) void gemm_bt(const unsigned short* __restrict__ A,
                                               const unsigned short* __restrict__ B,
                                               void* __restrict__ Cout,
                                               int M, int N, int K) {
  __shared__ __attribute__((aligned(16))) unsigned short Ah[128 * 64];
  __shared__ __attribute__((aligned(16))) unsigned short Bh[128 * 64];
  const int tid = threadIdx.x;
  const int l = tid & 63;
  const int w = tid >> 6;
  const int wm = w >> 1, wn = w & 1;
  const long brow = (long)blockIdx.y * 128;
  const long bcol = (long)blockIdx.x * 128;

  f32x4 acc[4][4];
#pragma unroll
  for (int i = 0; i < 4; ++i)
#pragma unroll
    for (int j = 0; j < 4; ++j) acc[i][j] = (f32x4){0.f, 0.f, 0.f, 0.f};

  const int srow = tid >> 3;
  const int sg = tid & 7;
  const int lwb = w << 10;

  for (int k0 = 0; k0 < K; k0 += 64) {
    __syncthreads();
#pragma unroll
    for (int i = 0; i < 4; ++i) {
      const int r = srow + i * 32;
      const int gp = (sg ^ (r & 7)) * 8;
      GLOAD16(A + (brow + r) * K + k0 + gp, (char*)Ah + lwb + i * 4096);
      GLOAD16(B + (bcol + r) * K + k0 + gp, (char*)Bh + lwb + i * 4096);
    }
    __syncthreads();
#pragma unroll
    for (int ks = 0; ks < 2; ++ks) {
      short8 af[4], bf[4];
#pragma unroll
      for (int mi = 0; mi < 4; ++mi) {
        const int row = wm * 64 + mi * 16 + (l & 15);
        const int byt = (row * 128 + (l >> 4) * 16 + ks * 64) ^ ((row & 7) << 4);
        af[mi] = *(const short8*)((const char*)Ah + byt);
      }
#pragma unroll
      for (int nj = 0; nj < 4; ++nj) {
        const int row = wn * 64 + nj * 16 + (l & 15);
        const int byt = (row * 128 + (l >> 4) * 16 + ks * 64) ^ ((row & 7) << 4);
        bf[nj] = *(const short8*)((const char*)Bh + byt);
      }
#pragma unroll
      for (int mi = 0; mi < 4; ++mi)
#pragma unroll
        for (int nj = 0; nj < 4; ++nj)
          acc[mi][nj] = __builtin_amdgcn_mfma_f32_16x16x32_bf16(af[mi], bf[nj],
                                                                acc[mi][nj], 0, 0, 0);
    }
  }

  const long rb = brow + wm * 64 + (l >> 4) * 4;
  const long cb = bcol + wn * 64 + (l & 15);
#pragma unroll
  for (int mi = 0; mi < 4; ++mi)
#pragma unroll
    for (int nj = 0; nj < 4; ++nj)
#pragma unroll
      for (int j = 0; j < 4; ++j) {
        const long row = rb + mi * 16 + j;
        const long col = cb + nj * 16;
        if (OUT_F32) ((float*)Cout)[row * N + col] = acc[mi][nj][j];
        else ((unsigned short*)Cout)[row * N + col] = f2bf(acc[mi][nj][j]);
      }
}

// -------------------------------------------------- sin/cos table (2048 x 64)
__global__ __launch_bounds__(256) void sincos_tab(float* __restrict__ tab) {
  int gid = blockIdx.x * 256 + threadIdx.x;  // 131072
  int t = gid >> 6, d = gid & 63;
  float inv = expf(-(float)(2 * d) * 0.07195578415606394f);
  float ang = (float)t * inv;
  tab[2 * gid]     = sinf(ang);
  tab[2 * gid + 1] = cosf(ang);
}

// ------------------------------------------------------------- RoPE on q,k
// thread = (m, h, d-block-of-8); table lookup, vectorized x8.
__global__ __launch_bounds__(256) void rope_qk(unsigned short* __restrict__ qkv,
                                               const float* __restrict__ tab) {
  int gid = blockIdx.x * 256 + threadIdx.x;  // 524288
  int m = gid >> 7;
  int h = (gid >> 3) & 15;
  int db = gid & 7;
  int t = m & 2047;
  long base = (long)m * 6144 + h * 128 + db * 8;
  const float* tp = tab + ((long)(t << 6) + db * 8) * 2;
  float4 t0 = *(const float4*)(tp + 0);
  float4 t1 = *(const float4*)(tp + 4);
  float4 t2 = *(const float4*)(tp + 8);
  float4 t3 = *(const float4*)(tp + 12);
  float sj[8] = {t0.x, t0.z, t1.x, t1.z, t2.x, t2.z, t3.x, t3.z};
  float cj[8] = {t0.y, t0.w, t1.y, t1.w, t2.y, t2.w, t3.y, t3.w};

  unsigned short* qp = qkv + base;
  short8 q1 = *(short8*)qp, q2 = *(short8*)(qp + 64);
  short8 o1, o2;
#pragma unroll
  for (int j = 0; j < 8; ++j) {
    float a = bf2f((unsigned short)q1[j]), bq = bf2f((unsigned short)q2[j]);
    o1[j] = (short)f2bf(a * cj[j] - bq * sj[j]);
    o2[j] = (short)f2bf(bq * cj[j] + a * sj[j]);
  }
  *(short8*)qp = o1; *(short8*)(qp + 64) = o2;

  unsigned short* kp = qkv + base + 2048;
  short8 k1 = *(short8*)kp, k2 = *(short8*)(kp + 64);
#pragma unroll
  for (int j = 0; j < 8; ++j) {
    float a = bf2f((unsigned short)k1[j]), bk = bf2f((unsigned short)k2[j]);
    o1[j] = (short)f2bf(a * cj[j] - bk * sj[j]);
    o2[j] = (short)f2bf(bk * cj[j] + a * sj[j]);
  }
  *(short8*)kp = o1; *(short8*)(kp + 64) = o2;
}

// --------------------------------------------- V (b,t,h,d) -> Vt (bh, d, t)
__global__ __launch_bounds__(256) void transpose_v(const unsigned short* __restrict__ qkv,
                                                   unsigned short* __restrict__ vt) {
  __shared__ __attribute__((aligned(16))) unsigned short tile[32][136];
  int tid = threadIdx.x;
  int t0 = blockIdx.x * 32;
  int bh = blockIdx.y;
  int b = bh >> 4, h = bh & 15;
  {
    int tt = tid >> 3;
    int dcb = (tid & 7) * 16;
    const unsigned short* src = qkv + (long)(b * 2048 + t0 + tt) * 6144 + 4096 + h * 128 + dcb;
    *(short8*)&tile[tt][dcb]     = *(const short8*)src;
    *(short8*)&tile[tt][dcb + 8] = *(const short8*)(src + 8);
  }
  __syncthreads();
  {
    int d = tid >> 1;
    int ts = (tid & 1) * 16;
    short8 o0, o1;
#pragma unroll
    for (int i = 0; i < 8; ++i) o0[i] = (short)tile[ts + i][d];
#pragma unroll
    for (int i = 0; i < 8; ++i) o1[i] = (short)tile[ts + 8 + i][d];
    unsigned short* dst = vt + (long)bh * 262144 + (long)d * 2048 + t0 + ts;
    *(short8*)dst       = o0;
    *(short8*)(dst + 8) = o1;
  }
}

// ----------------------------------------------------------- flash attention
// 512 blocks (16 qt-pairs x 32 bh), 4 waves. Each block owns q-tiles
// (qtA, 31-qtA) sharing ONE KV loop + staged tiles; K/V double-buffered with
// prefetch (T3 minimal 2-phase): one __syncthreads per iter, vmcnt drain
// lands after a full compute phase. Ph is wave-private (lgkmcnt+sched_barrier
// ordering, rule #18). Q prescaled by scale*log2e -> exp2 directly.
#define STAGE(IT, BUF) do {                                                     \
    const int kv0s_ = (IT) * 64;                                                \
    _Pragma("unroll")                                                           \
    for (int i_ = 0; i_ < 4; ++i_) {                                            \
      const int kr_ = (tid >> 4) + i_ * 16;                                     \
      const int kgp_ = ((tid & 15) ^ (kr_ & 7)) * 8;                            \
      GLOAD16(qkv + (long)(b * 2048 + kv0s_ + kr_) * 6144 + 2048 + h * 128 + kgp_, \
              (char*)&Kh[BUF][0] + (w << 10) + i_ * 4096);                      \
      const int vr_ = (tid >> 3) + i_ * 32;                                     \
      const int vgp_ = ((tid & 7) ^ (vr_ & 7)) * 8;                             \
      GLOAD16(vt + (long)bh * 262144 + (long)vr_ * 2048 + kv0s_ + vgp_,         \
              (char*)&Vh[BUF][0] + (w << 10) + i_ * 4096);                      \
    }                                                                           \
  } while (0)

#define COMPUTE_TILE(QF, ACC, MR, LR, Q0, PHP, BUFB) do {                       \
    f32x4 s_[4];                                                                \
    _Pragma("unroll")                                                           \
    for (int kvt_ = 0; kvt_ < 4; ++kvt_) {                                      \
      s_[kvt_] = (f32x4){0.f, 0.f, 0.f, 0.f};                                   \
      _Pragma("unroll")                                                         \
      for (int dc_ = 0; dc_ < 4; ++dc_) {                                       \
        const int krow_ = kvt_ * 16 + (l & 15);                                 \
        const int byt_ = ((krow_ * 256 + (l >> 4) * 16 + dc_ * 64)              \
                          ^ ((krow_ & 7) << 4)) + (BUFB);                       \
        short8 kf_ = *(const short8*)((const char*)Kh + byt_);                  \
        s_[kvt_] = __builtin_amdgcn_mfma_f32_16x16x32_bf16(QF[dc_], kf_,        \
                                                           s_[kvt_], 0, 0, 0);  \
      }                                                                         \
    }                                                                           \
    const int qrc_ = (Q0) + w * 16 + ((l >> 4) << 2);                           \
    float mx_[4];                                                               \
    _Pragma("unroll") for (int j_ = 0; j_ < 4; ++j_) mx_[j_] = -1e30f;          \
    _Pragma("unroll")                                                           \
    for (int kvt_ = 0; kvt_ < 4; ++kvt_) {                                      \
      const int kvcol_ = kv0 + kvt_ * 16 + (l & 15);                            \
      _Pragma("unroll")                                                         \
      for (int j_ = 0; j_ < 4; ++j_) {                                          \
        float sv_ = s_[kvt_][j_];                                               \
        if (kvcol_ > qrc_ + j_) sv_ = -1e30f;                                   \
        s_[kvt_][j_] = sv_;                                                     \
        mx_[j_] = fmaxf(mx_[j_], sv_);                                          \
      }                                                                         \
    }                                                                           \
    float alpha_[4];                                                            \
    _Pragma("unroll")                                                           \
    for (int j_ = 0; j_ < 4; ++j_) {                                            \
      float v_ = mx_[j_];                                                       \
      v_ = fmaxf(v_, __shfl_xor(v_, 1));                                        \
      v_ = fmaxf(v_, __shfl_xor(v_, 2));                                        \
      v_ = fmaxf(v_, __shfl_xor(v_, 4));                                        \
      v_ = fmaxf(v_, __shfl_xor(v_, 8));                                        \
      float mnew_ = fmaxf((MR)[j_], v_);                                        \
      alpha_[j_] = exp2f((MR)[j_] - mnew_);                                     \
      (MR)[j_] = mnew_;                                                         \
    }                                                                           \
    float ps_[4] = {0.f, 0.f, 0.f, 0.f};                                        \
    _Pragma("unroll")                                                           \
    for (int kvt_ = 0; kvt_ < 4; ++kvt_) {                                      \
      _Pragma("unroll")                                                         \
      for (int j_ = 0; j_ < 4; ++j_) {                                          \
        float p_ = exp2f(s_[kvt_][j_] - (MR)[j_]);                              \
        ps_[j_] += p_;                                                          \
        const int prow_ = ((l >> 4) << 2) + j_;                                 \
        const int pcol_ = kvt_ * 16 + (l & 15);                                 \
        const int pb_ = (prow_ * 128 + pcol_ * 2) ^ ((prow_ & 7) << 4);         \
        *(unsigned short*)((char*)(PHP) + pb_) = f2bf(p_);                      \
      }                                                                         \
    }                                                                           \
    _Pragma("unroll")                                                           \
    for (int j_ = 0; j_ < 4; ++j_) {                                            \
      float v_ = ps_[j_];                                                       \
      v_ += __shfl_xor(v_, 1);                                                  \
      v_ += __shfl_xor(v_, 2);                                                  \
      v_ += __shfl_xor(v_, 4);                                                  \
      v_ += __shfl_xor(v_, 8);                                                  \
      (LR)[j_] = (LR)[j_] * alpha_[j_] + v_;                                    \
    }                                                                           \
    asm volatile("s_waitcnt lgkmcnt(0)" ::: "memory");                          \
    __builtin_amdgcn_sched_barrier(0);                                          \
    _Pragma("unroll")                                                           \
    for (int dn_ = 0; dn_ < 8; ++dn_)                                           \
      _Pragma("unroll")                                                         \
      for (int j_ = 0; j_ < 4; ++j_) (ACC)[dn_][j_] *= alpha_[j_];              \
    _Pragma("unroll")                                                           \
    for (int half_ = 0; half_ < 2; ++half_) {                                   \
      const int prw_ = (l & 15);                                                \
      const int pb_ = (prw_ * 128 + (l >> 4) * 16 + half_ * 64)                 \
                      ^ ((prw_ & 7) << 4);                                      \
      short8 pf_ = *(const short8*)((const char*)(PHP) + pb_);                  \
      _Pragma("unroll")                                                         \
      for (int dn_ = 0; dn_ < 8; ++dn_) {                                       \
        const int vrow_ = dn_ * 16 + (l & 15);                                  \
        const int vb_ = ((vrow_ * 128 + (l >> 4) * 16 + half_ * 64)             \
                         ^ ((vrow_ & 7) << 4)) + (BUFB);                        \
        short8 vf_ = *(const short8*)((const char*)Vh + vb_);                   \
        (ACC)[dn_] = __builtin_amdgcn_mfma_f32_16x16x32_bf16(pf_, vf_,          \
                                                             (ACC)[dn_], 0, 0, 0); \
      }                                                                         \
    }                                                                           \
  } while (0)

__global__ __launch_bounds__(256, 2) void flash_attn(const unsigned short* __restrict__ qkv,
                                                     const unsigned short* __restrict__ vt,
                                                     unsigned short* __restrict__ attn) {
  __shared__ __attribute__((aligned(16))) unsigned short Kh[2][64 * 128];   // 32KB
  __shared__ __attribute__((aligned(16))) unsigned short Vh[2][128 * 64];   // 32KB
  __shared__ __attribute__((aligned(16))) unsigned short Ph[4][2][16 * 64]; // 16KB

  const int tid = threadIdx.x;
  const int l = tid & 63;
  const int w = tid >> 6;
  const int bh = blockIdx.y;
  const int b = bh >> 4, h = bh & 15;
  const int qtA = blockIdx.x;        // 0..15 (heaviest pair first: nIter = 32-qtA)
  const int qtB = 31 - qtA;
  const int q0A = qtA * 64, q0B = qtB * 64;
  const int endA = q0A + 64;
  const int nIter = qtB + 1;
  const float qscale = 0.08838834764831845f * 1.4426950408889634f;  // 1/sqrt(D)*log2e

  short8 qfA[4], qfB[4];
  {
    const int qrA = q0A + w * 16 + (l & 15);
    const int qrB = q0B + w * 16 + (l & 15);
    const unsigned short* qpA = qkv + (long)(b * 2048 + qrA) * 6144 + h * 128 + (l >> 4) * 8;
    const unsigned short* qpB = qkv + (long)(b * 2048 + qrB) * 6144 + h * 128 + (l >> 4) * 8;
#pragma unroll
    for (int dc = 0; dc < 4; ++dc) {
      short8 va = *(const short8*)(qpA + dc * 32);
      short8 vb = *(const short8*)(qpB + dc * 32);
#pragma unroll
      for (int j = 0; j < 8; ++j) {
        va[j] = (short)f2bf(bf2f((unsigned short)va[j]) * qscale);
        vb[j] = (short)f2bf(bf2f((unsigned short)vb[j]) * qscale);
      }
      qfA[dc] = va; qfB[dc] = vb;
    }
  }

  f32x4 accA[8], accB[8];
#pragma unroll
  for (int i = 0; i < 8; ++i) {
    accA[i] = (f32x4){0.f, 0.f, 0.f, 0.f};
    accB[i] = (f32x4){0.f, 0.f, 0.f, 0.f};
  }
  float mA[4], lA[4], mB[4], lB[4];
#pragma unroll
  for (int j = 0; j < 4; ++j) { mA[j] = -INFINITY; lA[j] = 0.f; mB[j] = -INFINITY; lB[j] = 0.f; }

  STAGE(0, 0);
  __syncthreads();
  for (int it = 0; it < nIter; ++it) {
    const int kv0 = it * 64;
    if (it + 1 < nIter) STAGE(it + 1, (it + 1) & 1);
    const int bufb = (it & 1) * 16384;
    COMPUTE_TILE(qfB, accB, mB, lB, q0B, (char*)&Ph[w][0][0], bufb);
    if (kv0 < endA) COMPUTE_TILE(qfA, accA, mA, lA, q0A, (char*)&Ph[w][1][0], bufb);
    __syncthreads();
  }

  // epilogue (B,H,T,D layout to match reference transpose(0,2,1,3).reshape)
#pragma unroll
  for (int dn = 0; dn < 8; ++dn)
#pragma unroll
    for (int j = 0; j < 4; ++j) {
      const int qrowB = q0B + w * 16 + ((l >> 4) << 2) + j;
      const int qrowA = q0A + w * 16 + ((l >> 4) << 2) + j;
      const int d = dn * 16 + (l & 15);
      attn[((long)bh * 2048 + qrowB) * 128 + d] = f2bf(accB[dn][j] / lB[j]);
      attn[((long)bh * 2048 + qrowA) * 128 + d] = f2bf(accA[dn][j] / lA[j]);
    }
}

extern "C" void kernel_launch(void* const* d_in, const int* in_sizes, int n_in,
                              void* d_out, int out_size, void* d_ws, size_t ws_size,
                              hipStream_t stream) {
  (void)in_sizes; (void)n_in; (void)out_size; (void)ws_size;
  const float* x  = (const float*)d_in[0];
  const float* qw = (const float*)d_in[1];
  const float* ow = (const float*)d_in[2];
  float* out = (float*)d_out;
  char* ws = (char*)d_ws;

  // workspace overlay (peak 92,274,688 B):
  unsigned short* xb    = (unsigned short*)(ws + 0);          // 16.78 MB (phase 1)
  unsigned short* wqb   = (unsigned short*)(ws + 16777216);   // 25.17 MB (phase 1)
  unsigned short* qkvb  = (unsigned short*)(ws + 41943040);   // 50.33 MB
  float*          tabf  = (float*)(ws + 0);                   //  1.05 MB (phase 1b, dead xb)
  unsigned short* vtb   = (unsigned short*)(ws + 0);          // 16.78 MB (phase 2)
  unsigned short* attnb = (unsigned short*)(ws + 16777216);   // 16.78 MB (phase 2, BHTD)
  unsigned short* wob   = (unsigned short*)(ws + 33554432);   //  8.39 MB (phase 2)

  cvt_f32_bf16<<<4096, 256, 0, stream>>>(x, xb, 1048576);
  cvt_f32_bf16<<<6144, 256, 0, stream>>>(qw, wqb, 1572864);
  gemm_bt<0><<<dim3(48, 32), 256, 0, stream>>>(xb, wqb, (void*)qkvb, 4096, 6144, 2048);
  sincos_tab<<<512, 256, 0, stream>>>(tabf);                   // xb dead after gemm1
  cvt_f32_bf16<<<2048, 256, 0, stream>>>(ow, wob, 524288);
  rope_qk<<<2048, 256, 0, stream>>>(qkvb, tabf);
  transpose_v<<<dim3(64, 32), 256, 0, stream>>>(qkvb, vtb);    // tab dead after rope
  flash_attn<<<dim3(16, 32), 256, 0, stream>>>(qkvb, vtb, attnb);
  gemm_bt<1><<<dim3(16, 32), 256, 0, stream>>>(attnb, wob, (void*)out, 4096, 2048, 2048);
}